// Round 1
// baseline (145.848 us; speedup 1.0000x reference)
//
#include <hip/hip_runtime.h>
#include <hip/hip_bf16.h>

// Problem constants (BertMultiPooler: B=32, S=4096, H=768, K=64)
#define NB 32
#define NS 4096
#define NH 768
#define NK 64
#define NM (NB * NK)   // 2048 output rows
#define ND (2 * NH)    // 1536 GEMM reduction dim

typedef short short8 __attribute__((ext_vector_type(8)));
typedef float floatx4 __attribute__((ext_vector_type(4)));

__device__ __forceinline__ unsigned short f2bf(float f) {
    union { float f; unsigned u; } v; v.f = f;
    unsigned r = v.u + 0x7FFFu + ((v.u >> 16) & 1u);   // RNE to bf16
    return (unsigned short)(r >> 16);
}

// ---------------------------------------------------------------------------
// Kernel 1: build Wc[n][k] (bf16), n in [0,768), k in [0,1536):
//   k < 768  -> W_dense[n][k]
//   k >= 768 -> W_tab[n][k-768]
// ---------------------------------------------------------------------------
__global__ __launch_bounds__(256) void wconv_kernel(const float* __restrict__ Wd,
                                                    const float* __restrict__ Wt,
                                                    unsigned short* __restrict__ Wc) {
    int i = blockIdx.x * blockDim.x + threadIdx.x;   // float4-group index
    const int total = NH * ND / 4;                   // 294912
    if (i >= total) return;
    int e = i * 4;
    int n = e / ND;
    int k = e % ND;
    float4 v = (k < NH) ? *(const float4*)&Wd[n * NH + k]
                        : *(const float4*)&Wt[n * NH + (k - NH)];
    ushort4 o;
    o.x = f2bf(v.x); o.y = f2bf(v.y); o.z = f2bf(v.z); o.w = f2bf(v.w);
    *(ushort4*)&Wc[e] = o;
}

// ---------------------------------------------------------------------------
// Kernel 2: segment-mean pool + tab gather -> X (bf16, 2048 x 1536)
// One block per segment (contiguous row range). 192 threads, float4 per thread.
// ---------------------------------------------------------------------------
__global__ __launch_bounds__(192) void pool_kernel(const float* __restrict__ hs,
                                                   const int* __restrict__ cls,
                                                   const int* __restrict__ tlen,
                                                   unsigned short* __restrict__ X) {
    int seg = blockIdx.x;           // 0..2047
    int b   = seg >> 6;             // seg / K
    int k   = seg & 63;             // seg % K
    int start = cls[seg * 2 + 1];
    int end   = (k == NK - 1) ? NS : cls[seg * 2 + 3];
    int tl    = tlen[b];
    if (end > tl) end = tl;
    int cnt = end - start;
    if (cnt < 0) cnt = 0;

    int t = threadIdx.x;            // 0..191, handles columns 4t..4t+3
    const float4* row = (const float4*)(hs + ((size_t)b * NS + (size_t)start) * NH) + t;

    float4 a0 = {0,0,0,0}, a1 = {0,0,0,0}, a2 = {0,0,0,0}, a3 = {0,0,0,0};
    int r = 0;
    for (; r + 4 <= cnt; r += 4) {
        float4 v0 = row[(size_t)(r + 0) * (NH / 4)];
        float4 v1 = row[(size_t)(r + 1) * (NH / 4)];
        float4 v2 = row[(size_t)(r + 2) * (NH / 4)];
        float4 v3 = row[(size_t)(r + 3) * (NH / 4)];
        a0.x += v0.x; a0.y += v0.y; a0.z += v0.z; a0.w += v0.w;
        a1.x += v1.x; a1.y += v1.y; a1.z += v1.z; a1.w += v1.w;
        a2.x += v2.x; a2.y += v2.y; a2.z += v2.z; a2.w += v2.w;
        a3.x += v3.x; a3.y += v3.y; a3.z += v3.z; a3.w += v3.w;
    }
    for (; r < cnt; ++r) {
        float4 v0 = row[(size_t)r * (NH / 4)];
        a0.x += v0.x; a0.y += v0.y; a0.z += v0.z; a0.w += v0.w;
    }
    float4 acc;
    acc.x = a0.x + a1.x + a2.x + a3.x;
    acc.y = a0.y + a1.y + a2.y + a3.y;
    acc.z = a0.z + a1.z + a2.z + a3.z;
    acc.w = a0.w + a1.w + a2.w + a3.w;

    float inv = 1.0f / (float)cnt;   // cnt>=1 for valid inputs; cnt==0 -> NaN like ref

    // tab gather: row `start` of batch cls[seg*2] (== b for these inputs)
    int tb = cls[seg * 2];
    float4 tv = *((const float4*)(hs + ((size_t)tb * NS + (size_t)start) * NH) + t);

    ushort4 po, ta;
    po.x = f2bf(acc.x * inv); po.y = f2bf(acc.y * inv);
    po.z = f2bf(acc.z * inv); po.w = f2bf(acc.w * inv);
    ta.x = f2bf(tv.x); ta.y = f2bf(tv.y); ta.z = f2bf(tv.z); ta.w = f2bf(tv.w);

    unsigned short* xr = X + (size_t)seg * ND;
    *(ushort4*)&xr[t * 4]      = po;   // pooled half  [0,768)
    *(ushort4*)&xr[NH + t * 4] = ta;   // tab half     [768,1536)
}

// ---------------------------------------------------------------------------
// Kernel 3: out = tanh(X @ Wc^T + b_dense + b_tab)
// M=2048, N=768, K=1536, bf16 MFMA 16x16x32, f32 accumulate.
// Block tile 64x64 (4 waves, 2x2), BK=32. Grid (32, 12).
// LDS rows padded to 40 shorts (80B) -> 2-way-max bank aliasing (free).
// ---------------------------------------------------------------------------
__global__ __launch_bounds__(256) void gemm_kernel(const unsigned short* __restrict__ X,
                                                   const unsigned short* __restrict__ Wc,
                                                   const float* __restrict__ bd,
                                                   const float* __restrict__ bt,
                                                   float* __restrict__ out) {
    __shared__ unsigned short Al[64 * 40];
    __shared__ unsigned short Bl[64 * 40];

    const int m0 = blockIdx.x * 64;
    const int n0 = blockIdx.y * 64;
    const int tid  = threadIdx.x;
    const int lane = tid & 63;
    const int wv   = tid >> 6;
    const int wr   = wv >> 1;          // wave row (0..1)
    const int wc   = wv & 1;           // wave col (0..1)
    const int lrow = lane & 15;
    const int hi   = lane >> 4;        // 0..3
    const int srow   = tid >> 2;       // staging row 0..63
    const int schunk = tid & 3;        // staging 16B chunk 0..3

    floatx4 acc[2][2] = {};

    const uint4* gA = (const uint4*)(X  + (size_t)(m0 + srow) * ND) + schunk;
    const uint4* gB = (const uint4*)(Wc + (size_t)(n0 + srow) * ND) + schunk;

    uint4 va = gA[0];
    uint4 vb = gB[0];

    const int KT = ND / 32;            // 48
    for (int kt = 0; kt < KT; ++kt) {
        __syncthreads();               // previous iter's ds_reads done
        *(uint4*)&Al[srow * 40 + schunk * 8] = va;
        *(uint4*)&Bl[srow * 40 + schunk * 8] = vb;
        __syncthreads();

        if (kt + 1 < KT) {             // prefetch next tile while MFMAs run
            va = gA[(kt + 1) * 4];
            vb = gB[(kt + 1) * 4];
        }

        short8 a0 = *(const short8*)&Al[(wr * 32 +      lrow) * 40 + hi * 8];
        short8 a1 = *(const short8*)&Al[(wr * 32 + 16 + lrow) * 40 + hi * 8];
        short8 b0 = *(const short8*)&Bl[(wc * 32 +      lrow) * 40 + hi * 8];
        short8 b1 = *(const short8*)&Bl[(wc * 32 + 16 + lrow) * 40 + hi * 8];

        acc[0][0] = __builtin_amdgcn_mfma_f32_16x16x32_bf16(a0, b0, acc[0][0], 0, 0, 0);
        acc[0][1] = __builtin_amdgcn_mfma_f32_16x16x32_bf16(a0, b1, acc[0][1], 0, 0, 0);
        acc[1][0] = __builtin_amdgcn_mfma_f32_16x16x32_bf16(a1, b0, acc[1][0], 0, 0, 0);
        acc[1][1] = __builtin_amdgcn_mfma_f32_16x16x32_bf16(a1, b1, acc[1][1], 0, 0, 0);
    }

    // Epilogue: C/D layout col = lane&15, row = (lane>>4)*4 + reg  [HW-verified]
    for (int mi = 0; mi < 2; ++mi) {
        for (int ni = 0; ni < 2; ++ni) {
            int col  = n0 + wc * 32 + ni * 16 + lrow;
            float bias = bd[col] + bt[col];
            int rowb = m0 + wr * 32 + mi * 16 + hi * 4;
            #pragma unroll
            for (int j = 0; j < 4; ++j) {
                out[(size_t)(rowb + j) * NH + col] = tanhf(acc[mi][ni][j] + bias);
            }
        }
    }
}

// ---------------------------------------------------------------------------
extern "C" void kernel_launch(void* const* d_in, const int* in_sizes, int n_in,
                              void* d_out, int out_size, void* d_ws, size_t ws_size,
                              hipStream_t stream) {
    const float* hs  = (const float*)d_in[0];   // hidden_states (B,S,H) f32
    const float* Wd  = (const float*)d_in[1];   // W_dense (H,H)
    const float* bd  = (const float*)d_in[2];   // b_dense (H,)
    const float* Wt  = (const float*)d_in[3];   // W_tab (H,H)
    const float* bt  = (const float*)d_in[4];   // b_tab (H,)
    const int*   cls = (const int*)d_in[5];     // cls_indexes (B*K, 2)
    const int*   tl  = (const int*)d_in[6];     // table_length (B,)
    float* out = (float*)d_out;

    unsigned short* X  = (unsigned short*)d_ws;          // 2048*1536 bf16 = 6 MB
    unsigned short* Wc = X + (size_t)NM * ND;            // 768*1536 bf16 = 2.25 MB

    // weights convert (independent of pool)
    wconv_kernel<<<dim3((NH * ND / 4 + 255) / 256), 256, 0, stream>>>(Wd, Wt, Wc);
    // segment-mean pooling + tab gather
    pool_kernel<<<dim3(NM), 192, 0, stream>>>(hs, cls, tl, X);
    // fused GEMM + bias + tanh
    gemm_kernel<<<dim3(NM / 64, NH / 64), 256, 0, stream>>>(X, Wc, bd, bt, out);
}